// Round 3
// baseline (289.273 us; speedup 1.0000x reference)
//
#include <hip/hip_runtime.h>
#include <math.h>

#define N_   128
#define S_   1024
#define D_   128
#define SD_  (S_ * D_)     // 131072

typedef __attribute__((ext_vector_type(8))) short bf16x8;
typedef __attribute__((ext_vector_type(4))) short bf16x4;
typedef __attribute__((ext_vector_type(4))) float f32x4;
#define MFMA16 __builtin_amdgcn_mfma_f32_16x16x32_bf16

// pe(s): row i = s>>5, col c = s&31; arg = pi*i*1000^(-(c&~1)/128); sin if c even
__device__ __forceinline__ float pe_scale(int s) {
    int i = s >> 5;
    int c = s & 31;
    double rexp = pow(1000.0, -(double)(c & ~1) / 128.0);
    double arg = M_PI * (double)i * rexp;
    return (float)((c & 1) ? cos(arg) : sin(arg));
}

__device__ __forceinline__ unsigned short bf16_rn(float f) {
    unsigned int u = __float_as_uint(f);
    u += 0x7fff + ((u >> 16) & 1);
    return (unsigned short)(u >> 16);
}
__device__ __forceinline__ float bf16_f(unsigned short h) {
    return __uint_as_float(((unsigned int)h) << 16);
}
__device__ __forceinline__ void split2(float f, unsigned short& h, unsigned short& l) {
    h = bf16_rn(f);
    l = bf16_rn(f - bf16_f(h));
}

// load 8 consecutive fp32, scale, split into hi/lo bf16x8 frags
__device__ __forceinline__ void load_split8(const float* p, float scale,
                                            bf16x8& hi, bf16x8& lo) {
    float4 u0 = *(const float4*)(p);
    float4 u1 = *(const float4*)(p + 4);
    unsigned short h[8], l[8];
    split2(u0.x * scale, h[0], l[0]); split2(u0.y * scale, h[1], l[1]);
    split2(u0.z * scale, h[2], l[2]); split2(u0.w * scale, h[3], l[3]);
    split2(u1.x * scale, h[4], l[4]); split2(u1.y * scale, h[5], l[5]);
    split2(u1.z * scale, h[6], l[6]); split2(u1.w * scale, h[7], l[7]);
    hi = bf16x8{(short)h[0],(short)h[1],(short)h[2],(short)h[3],
                (short)h[4],(short)h[5],(short)h[6],(short)h[7]};
    lo = bf16x8{(short)l[0],(short)l[1],(short)l[2],(short)l[3],
                (short)l[4],(short)l[5],(short)l[6],(short)l[7]};
}

// ---------------------------------------------------------------------------
// K1: scores += q_s . k_s via split-bf16 MFMA. grid 512 x 256, 2 s per block.
// LDS: qk transpose buffer only (~41KB) -> 2 blocks/CU.
// xs held as register fragments; W split in-register from global.
// ---------------------------------------------------------------------------
__global__ __launch_bounds__(256, 2) void k_scores(const float* __restrict__ x,
                                                   const float* __restrict__ W,
                                                   const float* __restrict__ b,
                                                   float* __restrict__ scores) {
    __shared__ unsigned short qk[4][128 * 40];   // q_hi,q_lo,k_hi,k_lo : [n][r]
    __shared__ float bl[384];

    const int t    = threadIdx.x;
    const int lane = t & 63;
    const int wv   = t >> 6;        // wave 0..3
    const int lid  = lane & 15;
    const int quad = lane >> 4;

    if (t < 128) { bl[t] = b[t]; bl[t + 128] = b[t + 128]; bl[t + 256] = b[t + 256]; }
    __syncthreads();

    const f32x4 fzero = {0.f, 0.f, 0.f, 0.f};
    f32x4 sacc[2][8];
#pragma unroll
    for (int i = 0; i < 2; ++i)
#pragma unroll
        for (int j = 0; j < 8; ++j) sacc[i][j] = fzero;

    for (int si = 0; si < 2; ++si) {
        const int s = blockIdx.x * 2 + si;
        const float ps = pe_scale(s);

        // ---- held xs B-frags: rows n=(wv*2+nt)*16+lid, k=ks*32+quad*8 ----
        bf16x8 xh[2][4], xl[2][4];
#pragma unroll
        for (int nt = 0; nt < 2; ++nt) {
            const int row = (wv * 2 + nt) * 16 + lid;
            const float* xp = x + (size_t)row * SD_ + (size_t)s * D_;
#pragma unroll
            for (int ks = 0; ks < 4; ++ks)
                load_split8(xp + ks * 32 + quad * 8, ps, xh[nt][ks], xl[nt][ks]);
        }

        for (int rc = 0; rc < 4; ++rc) {
            // ---- projection: qT = Wp @ xs^T (3-term split), p=0:q 1:k ----
            for (int p = 0; p < 2; ++p) {
                f32x4 pacc[2][2];
                pacc[0][0] = fzero; pacc[0][1] = fzero;
                pacc[1][0] = fzero; pacc[1][1] = fzero;
#pragma unroll
                for (int ks = 0; ks < 4; ++ks) {
                    const int kofs = ks * 32 + quad * 8;
                    bf16x8 wh[2], wl[2];
#pragma unroll
                    for (int mt = 0; mt < 2; ++mt) {
                        const float* wp = W + (size_t)(3 * (rc * 32 + mt * 16 + lid) + p) * D_ + kofs;
                        load_split8(wp, 1.0f, wh[mt], wl[mt]);
                    }
#pragma unroll
                    for (int mt = 0; mt < 2; ++mt)
#pragma unroll
                        for (int nt = 0; nt < 2; ++nt) {
                            pacc[mt][nt] = MFMA16(wh[mt], xh[nt][ks], pacc[mt][nt], 0, 0, 0);
                            pacc[mt][nt] = MFMA16(wh[mt], xl[nt][ks], pacc[mt][nt], 0, 0, 0);
                            pacc[mt][nt] = MFMA16(wl[mt], xh[nt][ks], pacc[mt][nt], 0, 0, 0);
                        }
                }
                // epilogue: +bias, split, write transposed into qk[n][r]
#pragma unroll
                for (int mt = 0; mt < 2; ++mt)
#pragma unroll
                    for (int nt = 0; nt < 2; ++nt) {
                        const int n = (wv * 2 + nt) * 16 + lid;
                        unsigned short hh[4], ll[4];
#pragma unroll
                        for (int r = 0; r < 4; ++r) {
                            const int rg = rc * 32 + mt * 16 + quad * 4 + r;
                            float qv = pacc[mt][nt][r] + bl[3 * rg + p];
                            split2(qv, hh[r], ll[r]);
                        }
                        bf16x4 hv = {(short)hh[0], (short)hh[1], (short)hh[2], (short)hh[3]};
                        bf16x4 lv = {(short)ll[0], (short)ll[1], (short)ll[2], (short)ll[3]};
                        *(bf16x4*)&qk[p * 2 + 0][n * 40 + mt * 16 + quad * 4] = hv;
                        *(bf16x4*)&qk[p * 2 + 1][n * 40 + mt * 16 + quad * 4] = lv;
                    }
            }
            __syncthreads();
            // ---- scores += q @ k^T over this 32-r chunk (3-term split) ----
            {
                bf16x8 qh[2], ql[2];
#pragma unroll
                for (int mt = 0; mt < 2; ++mt) {
                    const int row = wv * 32 + mt * 16 + lid;
                    qh[mt] = *(const bf16x8*)&qk[0][row * 40 + quad * 8];
                    ql[mt] = *(const bf16x8*)&qk[1][row * 40 + quad * 8];
                }
#pragma unroll
                for (int ntp = 0; ntp < 8; ++ntp) {
                    const int row = ntp * 16 + lid;
                    bf16x8 kh = *(const bf16x8*)&qk[2][row * 40 + quad * 8];
                    bf16x8 kl = *(const bf16x8*)&qk[3][row * 40 + quad * 8];
#pragma unroll
                    for (int mt = 0; mt < 2; ++mt) {
                        sacc[mt][ntp] = MFMA16(qh[mt], kh, sacc[mt][ntp], 0, 0, 0);
                        sacc[mt][ntp] = MFMA16(qh[mt], kl, sacc[mt][ntp], 0, 0, 0);
                        sacc[mt][ntp] = MFMA16(ql[mt], kh, sacc[mt][ntp], 0, 0, 0);
                    }
                }
            }
            __syncthreads();   // protect qk before next rc overwrite
        }
    }
    // ---- atomic accumulate ----
#pragma unroll
    for (int mt = 0; mt < 2; ++mt)
#pragma unroll
        for (int ntp = 0; ntp < 8; ++ntp)
#pragma unroll
            for (int r = 0; r < 4; ++r) {
                const int n  = wv * 32 + mt * 16 + quad * 4 + r;
                const int np = ntp * 16 + lid;
                atomicAdd(&scores[n * N_ + np], sacc[mt][ntp][r]);
            }
}

// ---------------------------------------------------------------------------
// K2: attn = softmax(scores/sqrt(128)) -> bf16. grid 128 x 128 threads.
// ---------------------------------------------------------------------------
__global__ void k_softmax(const float* __restrict__ scores, unsigned short* __restrict__ attn_bf) {
    const int n = blockIdx.x;
    const int t = threadIdx.x;
    float v = scores[n * N_ + t] * 0.08838834764831845f;

    __shared__ float red[2];
    __shared__ float red2[2];

    float m = v;
#pragma unroll
    for (int o = 32; o > 0; o >>= 1) m = fmaxf(m, __shfl_xor(m, o));
    if ((t & 63) == 0) red[t >> 6] = m;
    __syncthreads();
    m = fmaxf(red[0], red[1]);

    float e = expf(v - m);
    float sum = e;
#pragma unroll
    for (int o = 32; o > 0; o >>= 1) sum += __shfl_xor(sum, o);
    if ((t & 63) == 0) red2[t >> 6] = sum;
    __syncthreads();
    sum = red2[0] + red2[1];

    attn_bf[n * N_ + t] = bf16_rn(e / sum);
}

// ---------------------------------------------------------------------------
// K3: out[n, s*128+r] = sum_n' attn[n,n'] * v_s[n',r]. grid 1024 x 256.
// LDS: vT only (~35KB) -> 2 blocks/CU. xs frags in regs, Wv/attn from global.
// ---------------------------------------------------------------------------
__global__ __launch_bounds__(256, 2) void k_out(const float* __restrict__ x,
                                                const float* __restrict__ W,
                                                const float* __restrict__ b,
                                                const unsigned short* __restrict__ attn_bf,
                                                float* __restrict__ out) {
    __shared__ unsigned short vT[128 * 136];     // [r][n'] bf16
    __shared__ float bv[128];

    const int t    = threadIdx.x;
    const int lane = t & 63;
    const int wv   = t >> 6;
    const int lid  = lane & 15;
    const int quad = lane >> 4;
    const int s    = blockIdx.x;
    const float ps = pe_scale(s);

    if (t < 128) bv[t] = b[3 * t + 2];
    __syncthreads();

    const f32x4 fzero = {0.f, 0.f, 0.f, 0.f};

    // ---- held xs A-frags: rows n=(wv*2+mt)*16+lid ----
    bf16x8 xh[2][4], xl[2][4];
#pragma unroll
    for (int mt = 0; mt < 2; ++mt) {
        const int row = (wv * 2 + mt) * 16 + lid;
        const float* xp = x + (size_t)row * SD_ + (size_t)s * D_;
#pragma unroll
        for (int ks = 0; ks < 4; ++ks)
            load_split8(xp + ks * 32 + quad * 8, ps, xh[mt][ks], xl[mt][ks]);
    }

    // ---- v-proj: v = xs @ Wv^T (3-term split); vT chunks disjoint, no syncs ----
    for (int rc = 0; rc < 4; ++rc) {
        f32x4 vacc[2][2];
        vacc[0][0] = fzero; vacc[0][1] = fzero; vacc[1][0] = fzero; vacc[1][1] = fzero;
#pragma unroll
        for (int ks = 0; ks < 4; ++ks) {
            const int kofs = ks * 32 + quad * 8;
            bf16x8 wh[2], wl[2];
#pragma unroll
            for (int nt = 0; nt < 2; ++nt) {
                const float* wp = W + (size_t)(3 * (rc * 32 + nt * 16 + lid) + 2) * D_ + kofs;
                load_split8(wp, 1.0f, wh[nt], wl[nt]);
            }
#pragma unroll
            for (int mt = 0; mt < 2; ++mt)
#pragma unroll
                for (int nt = 0; nt < 2; ++nt) {
                    vacc[mt][nt] = MFMA16(xh[mt][ks], wh[nt], vacc[mt][nt], 0, 0, 0);
                    vacc[mt][nt] = MFMA16(xh[mt][ks], wl[nt], vacc[mt][nt], 0, 0, 0);
                    vacc[mt][nt] = MFMA16(xl[mt][ks], wh[nt], vacc[mt][nt], 0, 0, 0);
                }
        }
#pragma unroll
        for (int mt = 0; mt < 2; ++mt)
#pragma unroll
            for (int nt = 0; nt < 2; ++nt) {
                const int r = rc * 32 + nt * 16 + lid;
                const float bias = bv[r];
                unsigned short hh[4];
#pragma unroll
                for (int i = 0; i < 4; ++i) hh[i] = bf16_rn(vacc[mt][nt][i] + bias);
                bf16x4 hv = {(short)hh[0], (short)hh[1], (short)hh[2], (short)hh[3]};
                *(bf16x4*)&vT[r * 136 + (wv * 2 + mt) * 16 + quad * 4] = hv;
            }
    }
    __syncthreads();

    // ---- PV: outT = vT @ attnT (plain bf16, attn B-frags from global) ----
    {
        f32x4 oacc[2][8];
#pragma unroll
        for (int i = 0; i < 2; ++i)
#pragma unroll
            for (int j = 0; j < 8; ++j) oacc[i][j] = fzero;
#pragma unroll
        for (int ks = 0; ks < 4; ++ks) {
            const int kofs = ks * 32 + quad * 8;
            bf16x8 a[2];
#pragma unroll
            for (int mt = 0; mt < 2; ++mt)
                a[mt] = *(const bf16x8*)&vT[((wv * 2 + mt) * 16 + lid) * 136 + kofs];
#pragma unroll
            for (int nt = 0; nt < 8; ++nt) {
                bf16x8 bb = *(const bf16x8*)&attn_bf[(nt * 16 + lid) * N_ + kofs];
#pragma unroll
                for (int mt = 0; mt < 2; ++mt)
                    oacc[mt][nt] = MFMA16(a[mt], bb, oacc[mt][nt], 0, 0, 0);
            }
        }
#pragma unroll
        for (int mt = 0; mt < 2; ++mt)
#pragma unroll
            for (int nt = 0; nt < 8; ++nt) {
                const int r = (wv * 2 + mt) * 16 + quad * 4;
                const int n = nt * 16 + lid;
                *(float4*)&out[(size_t)n * SD_ + (size_t)s * D_ + r] = *(float4*)&oacc[mt][nt];
            }
    }
}

// ---------------------------------------------------------------------------
extern "C" void kernel_launch(void* const* d_in, const int* in_sizes, int n_in,
                              void* d_out, int out_size, void* d_ws, size_t ws_size,
                              hipStream_t stream) {
    const float* x = (const float*)d_in[0];
    const float* W = (const float*)d_in[1];
    const float* b = (const float*)d_in[2];
    float* out = (float*)d_out;
    float* scores = (float*)d_ws;                              // 64 KB
    unsigned short* attn_bf = (unsigned short*)((char*)d_ws + N_ * N_ * sizeof(float));  // 32 KB

    hipMemsetAsync(scores, 0, N_ * N_ * sizeof(float), stream);

    hipLaunchKernelGGL(k_scores, dim3(512), dim3(256), 0, stream, x, W, b, scores);
    hipLaunchKernelGGL(k_softmax, dim3(N_), dim3(128), 0, stream, scores, attn_bf);
    hipLaunchKernelGGL(k_out, dim3(1024), dim3(256), 0, stream, x, W, b, attn_bf, out);
}

// Round 4
// 258.177 us; speedup vs baseline: 1.1204x; 1.1204x over previous
//
#include <hip/hip_runtime.h>
#include <math.h>

#define N_   128
#define S_   1024
#define D_   128
#define SD_  (S_ * D_)     // 131072

#define WSP_PLANE 49152    // 3*4*4*4*32*8  (one hi or lo plane, elements)
#define NREP 16

typedef __attribute__((ext_vector_type(8))) short bf16x8;
typedef __attribute__((ext_vector_type(4))) short bf16x4;
typedef __attribute__((ext_vector_type(4))) float f32x4;
#define MFMA16 __builtin_amdgcn_mfma_f32_16x16x32_bf16

// pe(s): row i = s>>5, col c = s&31; arg = pi*i*1000^(-(c&~1)/128); sin if c even
__device__ __forceinline__ float pe_scale(int s) {
    int i = s >> 5;
    int c = s & 31;
    double rexp = pow(1000.0, -(double)(c & ~1) / 128.0);
    double arg = M_PI * (double)i * rexp;
    return (float)((c & 1) ? cos(arg) : sin(arg));
}

__device__ __forceinline__ unsigned short bf16_rn(float f) {
    unsigned int u = __float_as_uint(f);
    u += 0x7fff + ((u >> 16) & 1);
    return (unsigned short)(u >> 16);
}
__device__ __forceinline__ float bf16_f(unsigned short h) {
    return __uint_as_float(((unsigned int)h) << 16);
}
__device__ __forceinline__ void split2(float f, unsigned short& h, unsigned short& l) {
    h = bf16_rn(f);
    l = bf16_rn(f - bf16_f(h));
}

// load 8 consecutive fp32, scale, split into hi/lo bf16x8 frags
__device__ __forceinline__ void load_split8(const float* p, float scale,
                                            bf16x8& hi, bf16x8& lo) {
    float4 u0 = *(const float4*)(p);
    float4 u1 = *(const float4*)(p + 4);
    unsigned short h[8], l[8];
    split2(u0.x * scale, h[0], l[0]); split2(u0.y * scale, h[1], l[1]);
    split2(u0.z * scale, h[2], l[2]); split2(u0.w * scale, h[3], l[3]);
    split2(u1.x * scale, h[4], l[4]); split2(u1.y * scale, h[5], l[5]);
    split2(u1.z * scale, h[6], l[6]); split2(u1.w * scale, h[7], l[7]);
    hi = bf16x8{(short)h[0],(short)h[1],(short)h[2],(short)h[3],
                (short)h[4],(short)h[5],(short)h[6],(short)h[7]};
    lo = bf16x8{(short)l[0],(short)l[1],(short)l[2],(short)l[3],
                (short)l[4],(short)l[5],(short)l[6],(short)l[7]};
}

// ---------------------------------------------------------------------------
// K0: split W (fp32 [384][128]) into hi/lo bf16 planes in MFMA-frag-swizzled
// layout Wsp[h][p][rc][ks][quad][m(32)][j(8)]. grid 192 x 256.
// ---------------------------------------------------------------------------
__global__ __launch_bounds__(256) void k_prep(const float* __restrict__ W,
                                              unsigned short* __restrict__ Wsp) {
    const int idx = blockIdx.x * 256 + threadIdx.x;  // 0..49151
    const int rg = idx >> 7;         // W row (feature f)
    const int d  = idx & 127;
    const int p  = rg % 3;
    const int r  = rg / 3;
    const int rc = r >> 5, m = r & 31;
    const int ks = d >> 5, quad = (d >> 3) & 3, j = d & 7;
    unsigned short h, l;
    split2(W[idx], h, l);
    const size_t off = (size_t)((((p * 4 + rc) * 4 + ks) * 4 + quad) * 32 + m) * 8 + j;
    Wsp[off] = h;
    Wsp[off + WSP_PLANE] = l;
}

// ---------------------------------------------------------------------------
// K1: scores_rep[s&15] += q_s . k_s via split-bf16 MFMA. grid 1024 x 256,
// 1 s per block. LDS: qk transpose buffer (~41KB). W from pre-split Wsp.
// ---------------------------------------------------------------------------
__global__ __launch_bounds__(256, 2) void k_scores(const float* __restrict__ x,
                                                   const unsigned short* __restrict__ Wsp,
                                                   const float* __restrict__ b,
                                                   float* __restrict__ scores_rep) {
    __shared__ unsigned short qk[4][128 * 40];   // q_hi,q_lo,k_hi,k_lo : [n][r]
    __shared__ float bl[384];

    const int t    = threadIdx.x;
    const int lane = t & 63;
    const int wv   = t >> 6;        // wave 0..3
    const int lid  = lane & 15;
    const int quad = lane >> 4;

    if (t < 128) { bl[t] = b[t]; bl[t + 128] = b[t + 128]; bl[t + 256] = b[t + 256]; }
    __syncthreads();

    const f32x4 fzero = {0.f, 0.f, 0.f, 0.f};
    f32x4 sacc[2][8];
#pragma unroll
    for (int i = 0; i < 2; ++i)
#pragma unroll
        for (int j = 0; j < 8; ++j) sacc[i][j] = fzero;

    const int s = blockIdx.x;
    const float ps = pe_scale(s);

    // ---- held xs B-frags: rows n=(wv*2+nt)*16+lid, k=ks*32+quad*8 ----
    bf16x8 xh[2][4], xl[2][4];
#pragma unroll
    for (int nt = 0; nt < 2; ++nt) {
        const int row = (wv * 2 + nt) * 16 + lid;
        const float* xp = x + (size_t)row * SD_ + (size_t)s * D_;
#pragma unroll
        for (int ks = 0; ks < 4; ++ks)
            load_split8(xp + ks * 32 + quad * 8, ps, xh[nt][ks], xl[nt][ks]);
    }

    for (int rc = 0; rc < 4; ++rc) {
        // ---- projection: qT = Wp @ xs^T (3-term split), p=0:q 1:k ----
        for (int p = 0; p < 2; ++p) {
            f32x4 pacc[2][2];
            pacc[0][0] = fzero; pacc[0][1] = fzero;
            pacc[1][0] = fzero; pacc[1][1] = fzero;
#pragma unroll
            for (int ks = 0; ks < 4; ++ks) {
                const unsigned short* wb =
                    Wsp + (size_t)(((p * 4 + rc) * 4 + ks) * 4 + quad) * 256;
                bf16x8 wh[2], wl[2];
#pragma unroll
                for (int mt = 0; mt < 2; ++mt) {
                    wh[mt] = *(const bf16x8*)(wb + (mt * 16 + lid) * 8);
                    wl[mt] = *(const bf16x8*)(wb + WSP_PLANE + (mt * 16 + lid) * 8);
                }
#pragma unroll
                for (int mt = 0; mt < 2; ++mt)
#pragma unroll
                    for (int nt = 0; nt < 2; ++nt) {
                        pacc[mt][nt] = MFMA16(wh[mt], xh[nt][ks], pacc[mt][nt], 0, 0, 0);
                        pacc[mt][nt] = MFMA16(wh[mt], xl[nt][ks], pacc[mt][nt], 0, 0, 0);
                        pacc[mt][nt] = MFMA16(wl[mt], xh[nt][ks], pacc[mt][nt], 0, 0, 0);
                    }
            }
            // epilogue: +bias, split, write transposed into qk[n][r]
#pragma unroll
            for (int mt = 0; mt < 2; ++mt)
#pragma unroll
                for (int nt = 0; nt < 2; ++nt) {
                    const int n = (wv * 2 + nt) * 16 + lid;
                    unsigned short hh[4], ll[4];
#pragma unroll
                    for (int r = 0; r < 4; ++r) {
                        const int rg = rc * 32 + mt * 16 + quad * 4 + r;
                        float qv = pacc[mt][nt][r] + bl[3 * rg + p];
                        split2(qv, hh[r], ll[r]);
                    }
                    bf16x4 hv = {(short)hh[0], (short)hh[1], (short)hh[2], (short)hh[3]};
                    bf16x4 lv = {(short)ll[0], (short)ll[1], (short)ll[2], (short)ll[3]};
                    *(bf16x4*)&qk[p * 2 + 0][n * 40 + mt * 16 + quad * 4] = hv;
                    *(bf16x4*)&qk[p * 2 + 1][n * 40 + mt * 16 + quad * 4] = lv;
                }
        }
        __syncthreads();
        // ---- scores += q @ k^T over this 32-r chunk (3-term split) ----
        {
            bf16x8 qh[2], ql[2];
#pragma unroll
            for (int mt = 0; mt < 2; ++mt) {
                const int row = wv * 32 + mt * 16 + lid;
                qh[mt] = *(const bf16x8*)&qk[0][row * 40 + quad * 8];
                ql[mt] = *(const bf16x8*)&qk[1][row * 40 + quad * 8];
            }
#pragma unroll
            for (int ntp = 0; ntp < 8; ++ntp) {
                const int row = ntp * 16 + lid;
                bf16x8 kh = *(const bf16x8*)&qk[2][row * 40 + quad * 8];
                bf16x8 kl = *(const bf16x8*)&qk[3][row * 40 + quad * 8];
#pragma unroll
                for (int mt = 0; mt < 2; ++mt) {
                    sacc[mt][ntp] = MFMA16(qh[mt], kh, sacc[mt][ntp], 0, 0, 0);
                    sacc[mt][ntp] = MFMA16(qh[mt], kl, sacc[mt][ntp], 0, 0, 0);
                    sacc[mt][ntp] = MFMA16(ql[mt], kh, sacc[mt][ntp], 0, 0, 0);
                }
            }
        }
        __syncthreads();   // protect qk before next rc overwrite
    }
    // ---- atomic accumulate into this block's replica ----
    float* rep = scores_rep + (size_t)(s & (NREP - 1)) * (N_ * N_);
#pragma unroll
    for (int mt = 0; mt < 2; ++mt)
#pragma unroll
        for (int ntp = 0; ntp < 8; ++ntp)
#pragma unroll
            for (int r = 0; r < 4; ++r) {
                const int n  = wv * 32 + mt * 16 + quad * 4 + r;
                const int np = ntp * 16 + lid;
                atomicAdd(&rep[n * N_ + np], sacc[mt][ntp][r]);
            }
}

// ---------------------------------------------------------------------------
// K2: sum replicas, softmax, write attn pre-swizzled into B-frag layout
// att2[ks][quad][n][j]. grid 128 x 128 threads.
// ---------------------------------------------------------------------------
__global__ void k_softmax(const float* __restrict__ scores_rep,
                          unsigned short* __restrict__ att2) {
    const int n = blockIdx.x;
    const int t = threadIdx.x;
    float v = 0.0f;
#pragma unroll
    for (int rep = 0; rep < NREP; ++rep)
        v += scores_rep[(size_t)rep * (N_ * N_) + n * N_ + t];
    v *= 0.08838834764831845f;   // 1/sqrt(128)

    __shared__ float red[2];
    __shared__ float red2[2];

    float m = v;
#pragma unroll
    for (int o = 32; o > 0; o >>= 1) m = fmaxf(m, __shfl_xor(m, o));
    if ((t & 63) == 0) red[t >> 6] = m;
    __syncthreads();
    m = fmaxf(red[0], red[1]);

    float e = expf(v - m);
    float sum = e;
#pragma unroll
    for (int o = 32; o > 0; o >>= 1) sum += __shfl_xor(sum, o);
    if ((t & 63) == 0) red2[t >> 6] = sum;
    __syncthreads();
    sum = red2[0] + red2[1];

    const int ks = t >> 5, quad = (t >> 3) & 3, j = t & 7;
    att2[(size_t)(((ks * 4 + quad) * 128) + n) * 8 + j] = bf16_rn(e / sum);
}

// ---------------------------------------------------------------------------
// K3: out[n, s*128+r] = sum_n' attn[n,n'] * v_s[n',r]. grid 1024 x 256.
// LDS: vT only (~35KB). Wv from pre-split Wsp (p=2), attn from att2.
// ---------------------------------------------------------------------------
__global__ __launch_bounds__(256, 2) void k_out(const float* __restrict__ x,
                                                const unsigned short* __restrict__ Wsp,
                                                const float* __restrict__ b,
                                                const unsigned short* __restrict__ att2,
                                                float* __restrict__ out) {
    __shared__ unsigned short vT[128 * 136];     // [r][n'] bf16
    __shared__ float bv[128];

    const int t    = threadIdx.x;
    const int lane = t & 63;
    const int wv   = t >> 6;
    const int lid  = lane & 15;
    const int quad = lane >> 4;
    const int s    = blockIdx.x;
    const float ps = pe_scale(s);

    if (t < 128) bv[t] = b[3 * t + 2];
    __syncthreads();

    const f32x4 fzero = {0.f, 0.f, 0.f, 0.f};

    // ---- held xs A-frags: rows n=(wv*2+mt)*16+lid ----
    bf16x8 xh[2][4], xl[2][4];
#pragma unroll
    for (int mt = 0; mt < 2; ++mt) {
        const int row = (wv * 2 + mt) * 16 + lid;
        const float* xp = x + (size_t)row * SD_ + (size_t)s * D_;
#pragma unroll
        for (int ks = 0; ks < 4; ++ks)
            load_split8(xp + ks * 32 + quad * 8, ps, xh[mt][ks], xl[mt][ks]);
    }

    // ---- v-proj: v = xs @ Wv^T (3-term split); vT chunks disjoint, no syncs ----
    for (int rc = 0; rc < 4; ++rc) {
        f32x4 vacc[2][2];
        vacc[0][0] = fzero; vacc[0][1] = fzero; vacc[1][0] = fzero; vacc[1][1] = fzero;
#pragma unroll
        for (int ks = 0; ks < 4; ++ks) {
            const unsigned short* wb =
                Wsp + (size_t)(((2 * 4 + rc) * 4 + ks) * 4 + quad) * 256;
            bf16x8 wh[2], wl[2];
#pragma unroll
            for (int nt = 0; nt < 2; ++nt) {
                wh[nt] = *(const bf16x8*)(wb + (nt * 16 + lid) * 8);
                wl[nt] = *(const bf16x8*)(wb + WSP_PLANE + (nt * 16 + lid) * 8);
            }
#pragma unroll
            for (int mt = 0; mt < 2; ++mt)
#pragma unroll
                for (int nt = 0; nt < 2; ++nt) {
                    vacc[mt][nt] = MFMA16(xh[mt][ks], wh[nt], vacc[mt][nt], 0, 0, 0);
                    vacc[mt][nt] = MFMA16(xh[mt][ks], wl[nt], vacc[mt][nt], 0, 0, 0);
                    vacc[mt][nt] = MFMA16(xl[mt][ks], wh[nt], vacc[mt][nt], 0, 0, 0);
                }
        }
#pragma unroll
        for (int mt = 0; mt < 2; ++mt)
#pragma unroll
            for (int nt = 0; nt < 2; ++nt) {
                const int r = rc * 32 + nt * 16 + lid;
                const float bias = bv[r];
                unsigned short hh[4];
#pragma unroll
                for (int i = 0; i < 4; ++i) hh[i] = bf16_rn(vacc[mt][nt][i] + bias);
                bf16x4 hv = {(short)hh[0], (short)hh[1], (short)hh[2], (short)hh[3]};
                *(bf16x4*)&vT[r * 136 + (wv * 2 + mt) * 16 + quad * 4] = hv;
            }
    }
    __syncthreads();

    // ---- PV: outT = vT @ attnT (plain bf16, attn B-frags from att2) ----
    {
        f32x4 oacc[2][8];
#pragma unroll
        for (int i = 0; i < 2; ++i)
#pragma unroll
            for (int j = 0; j < 8; ++j) oacc[i][j] = fzero;
#pragma unroll
        for (int ks = 0; ks < 4; ++ks) {
            const int kofs = ks * 32 + quad * 8;
            bf16x8 a[2];
#pragma unroll
            for (int mt = 0; mt < 2; ++mt)
                a[mt] = *(const bf16x8*)&vT[((wv * 2 + mt) * 16 + lid) * 136 + kofs];
#pragma unroll
            for (int nt = 0; nt < 8; ++nt) {
                bf16x8 bb = *(const bf16x8*)&att2[(size_t)(((ks * 4 + quad) * 128) +
                                                           (nt * 16 + lid)) * 8];
#pragma unroll
                for (int mt = 0; mt < 2; ++mt)
                    oacc[mt][nt] = MFMA16(a[mt], bb, oacc[mt][nt], 0, 0, 0);
            }
        }
#pragma unroll
        for (int mt = 0; mt < 2; ++mt)
#pragma unroll
            for (int nt = 0; nt < 8; ++nt) {
                const int r = (wv * 2 + mt) * 16 + quad * 4;
                const int n = nt * 16 + lid;
                *(float4*)&out[(size_t)n * SD_ + (size_t)s * D_ + r] = *(float4*)&oacc[mt][nt];
            }
    }
}

// ---------------------------------------------------------------------------
extern "C" void kernel_launch(void* const* d_in, const int* in_sizes, int n_in,
                              void* d_out, int out_size, void* d_ws, size_t ws_size,
                              hipStream_t stream) {
    const float* x = (const float*)d_in[0];
    const float* W = (const float*)d_in[1];
    const float* b = (const float*)d_in[2];
    float* out = (float*)d_out;

    // ws layout: scores_rep [16][128][128] f32 (1 MB) | att2 32 KB | Wsp 192 KB
    float* scores_rep = (float*)d_ws;
    unsigned short* att2 = (unsigned short*)((char*)d_ws + NREP * N_ * N_ * sizeof(float));
    unsigned short* Wsp  = (unsigned short*)((char*)att2 + N_ * N_ * sizeof(unsigned short));

    hipMemsetAsync(scores_rep, 0, NREP * N_ * N_ * sizeof(float), stream);

    hipLaunchKernelGGL(k_prep,    dim3(192),  dim3(256), 0, stream, W, Wsp);
    hipLaunchKernelGGL(k_scores,  dim3(1024), dim3(256), 0, stream, x, Wsp, b, scores_rep);
    hipLaunchKernelGGL(k_softmax, dim3(N_),   dim3(128), 0, stream, scores_rep, att2);
    hipLaunchKernelGGL(k_out,     dim3(1024), dim3(256), 0, stream, x, Wsp, b, att2, out);
}